// Round 1
// baseline (495.490 us; speedup 1.0000x reference)
//
#include <hip/hip_runtime.h>

// CombinedLoss: 0.7*MSE + 0.3*mean_b softDTW_gamma.  B=64, T=1024, C=8, fp32.
// R8: 2 halves/batch x 64 batches = 128 blocks x 512 thr (8 waves).
// Same 1024-wave parallelism as R7 but 2 waves/SIMD -> SMT fills the
// dependency-chain stalls that left VALUBusy at 24% with 1 wave/SIMD.
// Cross-block halo boundaries per batch: 3 -> 1 (only at row 512); all other
// halos are intra-block LDS rings. Global wave g=8h+w_ owns rows [64g,64g+63];
// absolute 16-diag windows; wave g lags g-1 by 1 window (+1 at block boundary).
// Cross-block halo: self-validating 8B atomics ((tag k)<<32 | bits), relaxed
// agent scope, per-lane tag spin + 1-window prefetch.
// t-columns flow through lanes via DPP (no per-lane LDS reads in DP loop).
// ws: [0,128) mse | [256,320) sdtw | u64 rings @ float-offset 320 (~557 KB).

constexpr int TT = 1024;
constexpr float ALPHA_ = 0.7f;
constexpr float FINF = 1000000000.0f;
constexpr int RING = 1088;
constexpr int NSTEPS = 144;

__device__ __forceinline__ float shflup1(float old0, float v) {
    return __int_as_float(__builtin_amdgcn_update_dpp(
        __float_as_int(old0), __float_as_int(v), 0x138, 0xf, 0xf, false));
}
__device__ __forceinline__ float rotdn1(float v) {
    return __int_as_float(__builtin_amdgcn_update_dpp(
        0, __float_as_int(v), 0x130, 0xf, 0xf, false));
}

__global__ __launch_bounds__(512) void sdtw_band_kernel(
    const float* __restrict__ pred, const float* __restrict__ target,
    float* __restrict__ ws)
{
    __shared__ float4 s_p4[TT * 2];    // col j: [-2t0..3],[-2t4..7]
    __shared__ float  s_y2[TT];
    __shared__ float  s_ring[8][64];   // per-wave bottom-row ring
    __shared__ float  s_scr[84];       // scratch sink for non-lane63 writes
    __shared__ float  s_red[8];

    const int blk = blockIdx.x;
    const int b   = blk & 63;                  // batch (h*64+b: same-XCD halves)
    const int h   = blk >> 6;                  // half: rows [512h, 512h+511]
    const int tid = threadIdx.x;
    const int l   = tid & 63;
    const int w_  = __builtin_amdgcn_readfirstlane(tid >> 6);   // 0..7
    const int g   = (h << 3) + w_;             // global wave 0..15
    const int gbase = g << 6;
    const int row   = gbase + l;

    const float* pr = pred   + ((size_t)b * TT + row) * 8;
    const float* tr = target + ((size_t)b * TT + row) * 8;
    const float4 pa = ((const float4*)pr)[0];
    const float4 pb = ((const float4*)pr)[1];
    const float4 ma = ((const float4*)tr)[0];
    const float4 mb = ((const float4*)tr)[1];

    float x2 = 0.f, msep = 0.f;
    {
        const float pp[8] = {pa.x,pa.y,pa.z,pa.w,pb.x,pb.y,pb.z,pb.w};
        const float tt[8] = {ma.x,ma.y,ma.z,ma.w,mb.x,mb.y,mb.z,mb.w};
        #pragma unroll
        for (int c = 0; c < 8; ++c) {
            x2 = fmaf(pp[c], pp[c], x2);
            float d = pp[c] - tt[c];
            msep = fmaf(d, d, msep);
        }
    }
    // stage all 1024 columns (2 per thread)
    const float* tg = target + (size_t)b * TT * 8;
    #pragma unroll
    for (int c0 = 0; c0 < 2; ++c0) {
        const int col = tid + (c0 << 9);
        const float4 u0 = ((const float4*)(tg + (size_t)col * 8))[0];
        const float4 u1 = ((const float4*)(tg + (size_t)col * 8))[1];
        s_p4[2*col]   = make_float4(-2.f*u0.x, -2.f*u0.y, -2.f*u0.z, -2.f*u0.w);
        s_p4[2*col+1] = make_float4(-2.f*u1.x, -2.f*u1.y, -2.f*u1.z, -2.f*u1.w);
        s_y2[col] = u0.x*u0.x + u0.y*u0.y + u0.z*u0.z + u0.w*u0.w
                  + u1.x*u1.x + u1.y*u1.y + u1.z*u1.z + u1.w*u1.w;
    }
    #pragma unroll
    for (int off = 32; off > 0; off >>= 1) msep += __shfl_down(msep, off, 64);
    if (l == 0) s_red[w_] = msep;
    __syncthreads();
    if (tid == 0) {
        float s0 = 0.f;
        #pragma unroll
        for (int i = 0; i < 8; ++i) s0 += s_red[i];
        ws[blk] = s0;
    }

    unsigned long long* rings = (unsigned long long*)(ws + 320);
    unsigned long long* pub = rings + (size_t)b * RING;   // w_==7, h==0
    unsigned long long* con = rings + (size_t)b * RING;   // w_==0, h==1
    const int kb_pub   = 448;                 // 16 * amin(g=7)
    const int kb_con   = 448;
    const int kmax_con = kb_con + 1086;

    const float c1 = 7.213475204444817f;     // log2(e)/gamma
    const float c2 = 0.13862943611198906f;   // gamma*ln(2)
    const int amin = g << 2;                 // first abs window = 4g
    const int amax = amin + 67;

    float r1 = FINF, r2 = FINF;
    float tf0=0,tf1=0,tf2=0,tf3=0,tf4=0,tf5=0,tf6=0,tf7=0, y2f=0;
    int jj0 = 0;                             // column held in A0/B0/ya
    float4 A0 = s_p4[0], B0 = s_p4[1], A1 = s_p4[2], B1 = s_p4[3];
    float  ya = s_y2[0], yb = s_y2[1];
    unsigned long long pe1 = 0, pe2 = 0;
    int ppf = 0;

    for (int s = 0; s < NSTEPS; ++s) {
        const int a = s - g - h;                     // scalar window id
        if (a >= amin && a <= amax) {
            const int k0 = a << 4;
            const int u  = a - amin;                 // 0..67
            const int ndv = (u == 67) ? 14 : 15;     // last diag offset

            // ---- stage halo hv (diag k-1) / hvd (diag k-2), row gbase-1 ----
            float hv, hvd;
            if (w_ == 0) {
                if (h == 0) {
                    hv  = FINF;
                    hvd = (u == 0 && l == 0) ? 0.0f : FINF;
                } else {
                    const int kk1 = k0 - 1 + l, kk2 = k0 - 2 + l;
                    const int id1 = min(kk1 - kb_con, RING - 1);
                    const int id2 = min(kk2 - kb_con, RING - 1);
                    const bool n1 = (l < 16) && (kk1 <= kmax_con);
                    const bool n2 = (l < 16) && (kk2 <= kmax_con);
                    unsigned long long e1, e2;
                    if (ppf) { e1 = pe1; e2 = pe2; ppf = 0; }
                    else {
                        e1 = __hip_atomic_load(con + id1, __ATOMIC_RELAXED,
                                               __HIP_MEMORY_SCOPE_AGENT);
                        e2 = __hip_atomic_load(con + id2, __ATOMIC_RELAXED,
                                               __HIP_MEMORY_SCOPE_AGENT);
                    }
                    while (!__all(((!n1) | ((int)(e1 >> 32) == kk1)) &
                                  ((!n2) | ((int)(e2 >> 32) == kk2)))) {
                        e1 = __hip_atomic_load(con + id1, __ATOMIC_RELAXED,
                                               __HIP_MEMORY_SCOPE_AGENT);
                        e2 = __hip_atomic_load(con + id2, __ATOMIC_RELAXED,
                                               __HIP_MEMORY_SCOPE_AGENT);
                    }
                    hv  = n1 ? __uint_as_float((unsigned)e1) : FINF;
                    hvd = n2 ? __uint_as_float((unsigned)e2) : FINF;
                }
            } else {
                hv  = s_ring[w_ - 1][(k0 - 1 + l) & 63];
                hvd = s_ring[w_ - 1][(k0 - 2 + l) & 63];
            }
            float* wrp = (l == 63) ? &s_ring[w_][k0 & 63] : &s_scr[l];

            auto diag = [&](int d, bool edge_) {
                tf0 = shflup1(A0.x, tf0); tf1 = shflup1(A0.y, tf1);
                tf2 = shflup1(A0.z, tf2); tf3 = shflup1(A0.w, tf3);
                tf4 = shflup1(B0.x, tf4); tf5 = shflup1(B0.y, tf5);
                tf6 = shflup1(B0.z, tf6); tf7 = shflup1(B0.w, tf7);
                y2f = shflup1(ya, y2f);
                const float up   = shflup1(hv,  r1);
                const float dg   = shflup1(hvd, r2);
                const float left = r1;
                hv = rotdn1(hv); hvd = rotdn1(hvd);
                A0 = A1; B0 = B1; ya = yb;
                jj0 = min(jj0 + 1, TT - 1);
                const int jn = min(jj0 + 1, TT - 1);
                A1 = s_p4[2*jn]; B1 = s_p4[2*jn + 1]; yb = s_y2[jn];
                // split dot-product into two chains (depth 4+1)
                float acc  = x2 + y2f;
                float acc2 = 0.f;
                acc  = fmaf(pa.x, tf0, acc);  acc2 = fmaf(pa.y, tf1, acc2);
                acc  = fmaf(pa.z, tf2, acc);  acc2 = fmaf(pa.w, tf3, acc2);
                acc  = fmaf(pb.x, tf4, acc);  acc2 = fmaf(pb.y, tf5, acc2);
                acc  = fmaf(pb.z, tf6, acc);  acc2 = fmaf(pb.w, tf7, acc2);
                acc += acc2;
                const float m  = fminf(fminf(up, left), dg);
                const float M  = fmaxf(fmaxf(up, left), dg);
                const float md = __builtin_amdgcn_fmed3f(up, left, dg);
                const float mc = m * c1;
                const float e1 = __builtin_amdgcn_exp2f(fmaf(md, -c1, mc));
                const float e2 = __builtin_amdgcn_exp2f(fmaf(M,  -c1, mc));
                const float lg = __builtin_amdgcn_logf(1.0f + (e1 + e2));
                float rn = acc + fmaf(-c2, lg, m);
                if (edge_) {
                    const int jj = k0 + d - row;
                    rn = ((unsigned)jj < (unsigned)TT) ? rn : FINF;
                }
                r2 = r1; r1 = rn;
                wrp[d] = rn;
            };

            if (u >= 4 && u <= 63) {
                #pragma unroll
                for (int d = 0; d < 16; ++d) diag(d, false);
            } else {
                for (int d = 0; d <= ndv; ++d) diag(d, true);
            }

            // ---- producer: publish window as self-validating u64 entries ----
            if (w_ == 7 && h == 0) {
                if (l <= ndv) {
                    const int kk = k0 + l;
                    const unsigned long long ev =
                        ((unsigned long long)(unsigned)kk << 32) |
                        (unsigned long long)__float_as_uint(s_ring[7][kk & 63]);
                    __hip_atomic_store(pub + (kk - kb_pub), ev,
                                       __ATOMIC_RELAXED, __HIP_MEMORY_SCOPE_AGENT);
                }
            }
            // ---- consumer: prefetch next window's halo entries ----
            if (w_ == 0 && h == 1 && a < amax) {
                const int k0n = k0 + 16;
                const int kk1 = k0n - 1 + l, kk2 = k0n - 2 + l;
                pe1 = __hip_atomic_load(con + min(kk1 - kb_con, RING - 1),
                                        __ATOMIC_RELAXED, __HIP_MEMORY_SCOPE_AGENT);
                pe2 = __hip_atomic_load(con + min(kk2 - kb_con, RING - 1),
                                        __ATOMIC_RELAXED, __HIP_MEMORY_SCOPE_AGENT);
                ppf = 1;
            }
        }
        __syncthreads();
    }
    if (h == 1 && tid == 511) ws[256 + b] = r1;      // r_{2T-2}(T-1)
}

__global__ __launch_bounds__(256) void finalize2_kernel(
    const float* __restrict__ ws, float* __restrict__ out)
{
    __shared__ float sm[4], ss[4];
    const int tid = threadIdx.x, l = tid & 63, w = tid >> 6;
    float m  = (tid < 128) ? ws[tid] : 0.f;
    float sd = (tid < 64) ? ws[256 + tid] : 0.f;
    #pragma unroll
    for (int off = 32; off > 0; off >>= 1) {
        m  += __shfl_down(m,  off, 64);
        sd += __shfl_down(sd, off, 64);
    }
    if (l == 0) { sm[w] = m; ss[w] = sd; }
    __syncthreads();
    if (tid == 0) {
        float M = sm[0] + sm[1] + sm[2] + sm[3];
        float S = ss[0] + ss[1] + ss[2] + ss[3];
        out[0] = ALPHA_ * (M / 524288.0f) + (1.0f - ALPHA_) * (S / 64.0f);
    }
}

extern "C" void kernel_launch(void* const* d_in, const int* in_sizes, int n_in,
                              void* d_out, int out_size, void* d_ws, size_t ws_size,
                              hipStream_t stream) {
    const float* pred   = (const float*)d_in[0];
    const float* target = (const float*)d_in[1];
    float* ws  = (float*)d_ws;
    float* out = (float*)d_out;

    sdtw_band_kernel<<<128, 512, 0, stream>>>(pred, target, ws);
    finalize2_kernel<<<1, 256, 0, stream>>>(ws, out);
}

// Round 2
// 424.915 us; speedup vs baseline: 1.1661x; 1.1661x over previous
//
#include <hip/hip_runtime.h>

// CombinedLoss: 0.7*MSE + 0.3*mean_b softDTW_gamma.  B=64, T=1024, C=8, fp32.
// R9: barrier-free wavefront pipeline. 256 blocks x 256 thr (4 waves/blk,
// 1 wave/SIMD) as R7, but NO per-step __syncthreads: R7/R8 counters showed
// ~70% of each 16-diag step was barrier drain (6.5k cy/step vs ~1.6k cy work).
// Waves free-run their 68 windows; intra-block halo via full-length LDS rows
// s_row[w][1088] (no wrap -> no back-pressure) + per-wave progress flag
// (release store after each window / acquire spin before each window).
// Cross-block halo: unchanged self-validating 8B atomics ((tag k)<<32 | bits),
// relaxed agent scope, per-lane tag spin + 1-window prefetch.
// t-columns flow through lanes via DPP; no per-lane LDS reads in DP loop.
// ws: [0,256) mse | [256,320) sdtw | u64 rings @ float-offset 320 (~1.6 MB).

constexpr int TT = 1024;
constexpr float ALPHA_ = 0.7f;
constexpr float FINF = 1000000000.0f;
constexpr int RING = 1088;

__device__ __forceinline__ float shflup1(float old0, float v) {
    return __int_as_float(__builtin_amdgcn_update_dpp(
        __float_as_int(old0), __float_as_int(v), 0x138, 0xf, 0xf, false));
}
__device__ __forceinline__ float rotdn1(float v) {
    return __int_as_float(__builtin_amdgcn_update_dpp(
        0, __float_as_int(v), 0x130, 0xf, 0xf, false));
}

__global__ __launch_bounds__(256) void sdtw_band_kernel(
    const float* __restrict__ pred, const float* __restrict__ target,
    float* __restrict__ ws)
{
    __shared__ float4 s_p4[TT * 2];      // col j: [-2t0..3],[-2t4..7]
    __shared__ float  s_y2[TT];
    __shared__ float  s_row[4][1088];    // per-wave bottom row, full length
    __shared__ float  s_scr[84];         // scratch sink for non-lane63 writes
    __shared__ float  s_red[4];
    __shared__ int    s_prog[4];         // last completed abs window per wave

    const int blk = blockIdx.x;
    const int b   = blk & 63;                  // batch (q*64+b: same-XCD bands)
    const int q   = blk >> 6;                  // band
    const int tid = threadIdx.x;
    const int l   = tid & 63;
    const int w_  = __builtin_amdgcn_readfirstlane(tid >> 6);
    const int g   = (q << 2) + w_;             // global wave 0..15
    const int gbase = g << 6;
    const int row   = gbase + l;

    if (tid < 4) s_prog[tid] = -1;

    const float* pr = pred   + ((size_t)b * TT + row) * 8;
    const float* tr = target + ((size_t)b * TT + row) * 8;
    const float4 pa = ((const float4*)pr)[0];
    const float4 pb = ((const float4*)pr)[1];
    const float4 ma = ((const float4*)tr)[0];
    const float4 mb = ((const float4*)tr)[1];

    float x2 = 0.f, msep = 0.f;
    {
        const float pp[8] = {pa.x,pa.y,pa.z,pa.w,pb.x,pb.y,pb.z,pb.w};
        const float tt[8] = {ma.x,ma.y,ma.z,ma.w,mb.x,mb.y,mb.z,mb.w};
        #pragma unroll
        for (int c = 0; c < 8; ++c) {
            x2 = fmaf(pp[c], pp[c], x2);
            float d = pp[c] - tt[c];
            msep = fmaf(d, d, msep);
        }
    }
    // stage all 1024 columns (4 per thread)
    const float* tg = target + (size_t)b * TT * 8;
    #pragma unroll
    for (int c0 = 0; c0 < 4; ++c0) {
        const int col = tid + (c0 << 8);
        const float4 u0 = ((const float4*)(tg + (size_t)col * 8))[0];
        const float4 u1 = ((const float4*)(tg + (size_t)col * 8))[1];
        s_p4[2*col]   = make_float4(-2.f*u0.x, -2.f*u0.y, -2.f*u0.z, -2.f*u0.w);
        s_p4[2*col+1] = make_float4(-2.f*u1.x, -2.f*u1.y, -2.f*u1.z, -2.f*u1.w);
        s_y2[col] = u0.x*u0.x + u0.y*u0.y + u0.z*u0.z + u0.w*u0.w
                  + u1.x*u1.x + u1.y*u1.y + u1.z*u1.z + u1.w*u1.w;
    }
    #pragma unroll
    for (int off = 32; off > 0; off >>= 1) msep += __shfl_down(msep, off, 64);
    if (l == 0) s_red[w_] = msep;
    __syncthreads();                      // the ONLY block-wide barrier
    if (tid == 0) ws[blk] = s_red[0] + s_red[1] + s_red[2] + s_red[3];

    unsigned long long* rings = (unsigned long long*)(ws + 320);
    unsigned long long* pub = rings + (size_t)(q * 64 + b) * RING;       // w_==3,q<3
    unsigned long long* con = rings + (size_t)((q - 1) * 64 + b) * RING; // w_==0,q>0
    const int kb_pub   = 256 * q + 192;
    const int kb_con   = 256 * q - 64;
    const int kmax_con = kb_con + 1086;

    const float c1 = 7.213475204444817f;     // log2(e)/gamma
    const float c2 = 0.13862943611198906f;   // gamma*ln(2)
    const int amin = g << 2;                 // first abs window = 4g
    const int amax = amin + 67;
    const int prodmax = amin + 63;           // producer wave's amax = 4(g-1)+67

    float r1 = FINF, r2 = FINF;
    float tf0=0,tf1=0,tf2=0,tf3=0,tf4=0,tf5=0,tf6=0,tf7=0, y2f=0;
    int jj0 = 0;                             // column held in A0/B0/ya
    float4 A0 = s_p4[0], B0 = s_p4[1], A1 = s_p4[2], B1 = s_p4[3];
    float  ya = s_y2[0], yb = s_y2[1];
    unsigned long long pe1 = 0, pe2 = 0;
    int ppf = 0;

    for (int a = amin; a <= amax; ++a) {
        const int k0 = a << 4;
        const int u  = a - amin;                 // 0..67
        const int ndv = (u == 67) ? 14 : 15;     // last diag offset

        // ---- stage halo hv (diag k-1) / hvd (diag k-2), row gbase-1 ----
        float hv, hvd;
        if (w_ == 0) {
            if (q == 0) {
                hv  = FINF;
                hvd = (u == 0 && l == 0) ? 0.0f : FINF;
            } else {
                const int kk1 = k0 - 1 + l, kk2 = k0 - 2 + l;
                const int id1 = min(kk1 - kb_con, RING - 1);
                const int id2 = min(kk2 - kb_con, RING - 1);
                const bool n1 = (l < 16) && (kk1 <= kmax_con);
                const bool n2 = (l < 16) && (kk2 <= kmax_con);
                unsigned long long e1, e2;
                if (ppf) { e1 = pe1; e2 = pe2; ppf = 0; }
                else {
                    e1 = __hip_atomic_load(con + id1, __ATOMIC_RELAXED,
                                           __HIP_MEMORY_SCOPE_AGENT);
                    e2 = __hip_atomic_load(con + id2, __ATOMIC_RELAXED,
                                           __HIP_MEMORY_SCOPE_AGENT);
                }
                while (!__all(((!n1) | ((int)(e1 >> 32) == kk1)) &
                              ((!n2) | ((int)(e2 >> 32) == kk2)))) {
                    e1 = __hip_atomic_load(con + id1, __ATOMIC_RELAXED,
                                           __HIP_MEMORY_SCOPE_AGENT);
                    e2 = __hip_atomic_load(con + id2, __ATOMIC_RELAXED,
                                           __HIP_MEMORY_SCOPE_AGENT);
                }
                hv  = n1 ? __uint_as_float((unsigned)e1) : FINF;
                hvd = n2 ? __uint_as_float((unsigned)e2) : FINF;
            }
        } else {
            // wait for intra-block producer wave w_-1 to finish window a
            const int need = (a < prodmax) ? a : prodmax;
            int pv;
            do {
                pv = __hip_atomic_load(&s_prog[w_ - 1], __ATOMIC_ACQUIRE,
                                       __HIP_MEMORY_SCOPE_WORKGROUP);
            } while (pv < need);
            const int bi = (u << 4) + 63 + l;         // idx of k0-1+l in producer row
            hv  = s_row[w_ - 1][min(bi,     1087)];
            hvd = s_row[w_ - 1][min(bi - 1, 1087)];
        }
        float* wrp = (l == 63) ? &s_row[w_][u << 4] : &s_scr[l];

        auto diag = [&](int d, bool edge_) {
            tf0 = shflup1(A0.x, tf0); tf1 = shflup1(A0.y, tf1);
            tf2 = shflup1(A0.z, tf2); tf3 = shflup1(A0.w, tf3);
            tf4 = shflup1(B0.x, tf4); tf5 = shflup1(B0.y, tf5);
            tf6 = shflup1(B0.z, tf6); tf7 = shflup1(B0.w, tf7);
            y2f = shflup1(ya, y2f);
            const float up   = shflup1(hv,  r1);
            const float dg   = shflup1(hvd, r2);
            const float left = r1;
            hv = rotdn1(hv); hvd = rotdn1(hvd);
            A0 = A1; B0 = B1; ya = yb;
            jj0 = min(jj0 + 1, TT - 1);
            const int jn = min(jj0 + 1, TT - 1);
            A1 = s_p4[2*jn]; B1 = s_p4[2*jn + 1]; yb = s_y2[jn];
            float acc  = x2 + y2f;
            float acc2 = 0.f;
            acc  = fmaf(pa.x, tf0, acc);  acc2 = fmaf(pa.y, tf1, acc2);
            acc  = fmaf(pa.z, tf2, acc);  acc2 = fmaf(pa.w, tf3, acc2);
            acc  = fmaf(pb.x, tf4, acc);  acc2 = fmaf(pb.y, tf5, acc2);
            acc  = fmaf(pb.z, tf6, acc);  acc2 = fmaf(pb.w, tf7, acc2);
            acc += acc2;
            const float m  = fminf(fminf(up, left), dg);
            const float M  = fmaxf(fmaxf(up, left), dg);
            const float md = __builtin_amdgcn_fmed3f(up, left, dg);
            const float mc = m * c1;
            const float e1 = __builtin_amdgcn_exp2f(fmaf(md, -c1, mc));
            const float e2 = __builtin_amdgcn_exp2f(fmaf(M,  -c1, mc));
            const float lg = __builtin_amdgcn_logf(1.0f + (e1 + e2));
            float rn = acc + fmaf(-c2, lg, m);
            if (edge_) {
                const int jj = k0 + d - row;
                rn = ((unsigned)jj < (unsigned)TT) ? rn : FINF;
            }
            r2 = r1; r1 = rn;
            wrp[d] = rn;
        };

        if (u >= 4 && u <= 63) {
            #pragma unroll
            for (int d = 0; d < 16; ++d) diag(d, false);
        } else {
            for (int d = 0; d <= ndv; ++d) diag(d, true);
        }

        // ---- producer: publish window as self-validating u64 entries ----
        if (w_ == 3 && q < 3) {
            if (l <= ndv) {
                const int kk = k0 + l;
                const unsigned long long ev =
                    ((unsigned long long)(unsigned)kk << 32) |
                    (unsigned long long)__float_as_uint(s_row[3][(u << 4) + l]);
                __hip_atomic_store(pub + (kk - kb_pub), ev,
                                   __ATOMIC_RELAXED, __HIP_MEMORY_SCOPE_AGENT);
            }
        }
        // ---- consumer: prefetch next window's halo entries ----
        if (w_ == 0 && q > 0 && a < amax) {
            const int k0n = k0 + 16;
            const int kk1 = k0n - 1 + l, kk2 = k0n - 2 + l;
            pe1 = __hip_atomic_load(con + min(kk1 - kb_con, RING - 1),
                                    __ATOMIC_RELAXED, __HIP_MEMORY_SCOPE_AGENT);
            pe2 = __hip_atomic_load(con + min(kk2 - kb_con, RING - 1),
                                    __ATOMIC_RELAXED, __HIP_MEMORY_SCOPE_AGENT);
            ppf = 1;
        }
        // ---- mark window complete for intra-block consumer ----
        if (w_ < 3 && l == 0) {
            __hip_atomic_store(&s_prog[w_], a, __ATOMIC_RELEASE,
                               __HIP_MEMORY_SCOPE_WORKGROUP);
        }
    }
    if (q == 3 && tid == 255) ws[256 + b] = r1;      // r_{2T-2}(T-1)
}

__global__ __launch_bounds__(256) void finalize2_kernel(
    const float* __restrict__ ws, float* __restrict__ out)
{
    __shared__ float sm[4], ss[4];
    const int tid = threadIdx.x, l = tid & 63, w = tid >> 6;
    float m  = ws[tid];
    float sd = (tid < 64) ? ws[256 + tid] : 0.f;
    #pragma unroll
    for (int off = 32; off > 0; off >>= 1) {
        m  += __shfl_down(m,  off, 64);
        sd += __shfl_down(sd, off, 64);
    }
    if (l == 0) { sm[w] = m; ss[w] = sd; }
    __syncthreads();
    if (tid == 0) {
        float M = sm[0] + sm[1] + sm[2] + sm[3];
        float S = ss[0] + ss[1] + ss[2] + ss[3];
        out[0] = ALPHA_ * (M / 524288.0f) + (1.0f - ALPHA_) * (S / 64.0f);
    }
}

extern "C" void kernel_launch(void* const* d_in, const int* in_sizes, int n_in,
                              void* d_out, int out_size, void* d_ws, size_t ws_size,
                              hipStream_t stream) {
    const float* pred   = (const float*)d_in[0];
    const float* target = (const float*)d_in[1];
    float* ws  = (float*)d_ws;
    float* out = (float*)d_out;

    sdtw_band_kernel<<<256, 256, 0, stream>>>(pred, target, ws);
    finalize2_kernel<<<1, 256, 0, stream>>>(ws, out);
}